// Round 2
// baseline (85.235 us; speedup 1.0000x reference)
//
#include <hip/hip_runtime.h>

#define NQ 4
#define DIM 16
#define SPT 4   // samples per thread in the contraction kernel

struct cplx { float r, i; };
__device__ inline cplx cmul(cplx a, cplx b) { return {a.r*b.r - a.i*b.i, a.r*b.i + a.i*b.r}; }
__device__ inline cplx cadd(cplx a, cplx b) { return {a.r + b.r, a.i + b.i}; }

// compile-time for-loop: guarantees every array index below is a constant
// (rule #20: runtime-indexed ext arrays go to scratch — this makes that
// impossible by construction, independent of unroll heuristics).
template<int I> struct ic { static constexpr int v = I; };
template<int N, typename F> __device__ __forceinline__ void sfor(F f) {
    if constexpr (N > 0) { sfor<N - 1>(f); f(ic<N - 1>{}); }
}

// t[9] = (1, cv, sv, cu, cu*cv, cu*sv, su, su*cv, su*sv)
__device__ __forceinline__ void build9(float u, float v, float* t) {
    float su, cu, sv, cv;
    __sincosf(u, &su, &cu);
    __sincosf(v, &sv, &cv);
    t[0] = 1.f;      t[1] = cv;      t[2] = sv;
    t[3] = cu;       t[4] = cu * cv; t[5] = cu * sv;
    t[6] = su;       t[7] = su * cv; t[8] = su * sv;
}

// ---------------- Kernel A: build the 324 trig-basis coefficients ----------------
//   out_w = sum_{e in {1,cos,sin}^4} K_w[e] * prod_q f_{e_q}(x_q)
//   K_w[e] = (1/16) sum_b A_w[b][b^m] * parity(b & d1)   (m=sin-bits, d1=cos-bits)
//   A_w[j][k] = sum_idx sign_w(idx) * (Ur[idx][j]Ur[idx][k] + Ui[idx][j]Ui[idx][k])
// One block; ~4 µs. Keeping it out of the hot kernel gives the contraction its
// own register allocation and trivially analyzable codegen.
__global__ __launch_bounds__(256) void setup_kernel(const float* __restrict__ wt,
                                                    float* __restrict__ gk) {
    __shared__ float Ur[DIM][DIM];
    __shared__ float Ui[DIM][DIM];
    __shared__ float A[4][DIM][DIM];

    int col = threadIdx.x;
    if (col < DIM) {
        float ar[DIM], ai[DIM];
#pragma unroll
        for (int i = 0; i < DIM; ++i) { ar[i] = 0.f; ai[i] = 0.f; }
        ar[col] = 1.f;
#pragma unroll
        for (int l = 0; l < 2; ++l) {
#pragma unroll
            for (int q = 0; q < NQ; ++q) {
                float tx = wt[(l * 4 + q) * 3 + 0];
                float ty = wt[(l * 4 + q) * 3 + 1];
                float tz = wt[(l * 4 + q) * 3 + 2];
                float cx, sx, cy, sy, cz, sz;
                __sincosf(0.5f * tx, &sx, &cx);
                __sincosf(0.5f * ty, &sy, &cy);
                __sincosf(0.5f * tz, &sz, &cz);
                cplx Rx[2][2] = {{{cx, 0.f}, {0.f, -sx}}, {{0.f, -sx}, {cx, 0.f}}};
                cplx Ry[2][2] = {{{cy, 0.f}, {-sy, 0.f}}, {{sy, 0.f}, {cy, 0.f}}};
                cplx Rz[2][2] = {{{cz, -sz}, {0.f, 0.f}}, {{0.f, 0.f}, {cz, sz}}};
                cplx T[2][2], G[2][2];
#pragma unroll
                for (int r = 0; r < 2; ++r)
#pragma unroll
                    for (int c = 0; c < 2; ++c)
                        T[r][c] = cadd(cmul(Ry[r][0], Rx[0][c]), cmul(Ry[r][1], Rx[1][c]));
#pragma unroll
                for (int r = 0; r < 2; ++r)
#pragma unroll
                    for (int c = 0; c < 2; ++c)
                        G[r][c] = cadd(cmul(Rz[r][0], T[0][c]), cmul(Rz[r][1], T[1][c]));
                int pos = 3 - q, mask = 1 << pos;
#pragma unroll
                for (int idx = 0; idx < DIM; ++idx) {
                    if (idx & mask) continue;
                    int i1 = idx | mask;
                    cplx a0 = {ar[idx], ai[idx]}, a1 = {ar[i1], ai[i1]};
                    cplx n0 = cadd(cmul(G[0][0], a0), cmul(G[0][1], a1));
                    cplx n1 = cadd(cmul(G[1][0], a0), cmul(G[1][1], a1));
                    ar[idx] = n0.r; ai[idx] = n0.i;
                    ar[i1] = n1.r;  ai[i1] = n1.i;
                }
            }
#pragma unroll
            for (int q = 0; q < NQ; ++q) {
                int cpos = 3 - q, tpos = 3 - ((q + 1) & 3);
                int tmask = 1 << tpos;
#pragma unroll
                for (int idx = 0; idx < DIM; ++idx) {
                    if (((idx >> cpos) & 1) && !((idx >> tpos) & 1)) {
                        int i1 = idx | tmask;
                        float tr = ar[idx]; ar[idx] = ar[i1]; ar[i1] = tr;
                        float ti = ai[idx]; ai[idx] = ai[i1]; ai[i1] = ti;
                    }
                }
            }
        }
#pragma unroll
        for (int i = 0; i < DIM; ++i) { Ur[i][col] = ar[i]; Ui[i][col] = ai[i]; }
    }
    __syncthreads();

    // A_w[j][k], one (j,k) per thread; 4 outputs share the products
    {
        int j = threadIdx.x >> 4, k = threadIdx.x & 15;
        float a0 = 0.f, a1 = 0.f, a2 = 0.f, a3 = 0.f;
#pragma unroll
        for (int idx = 0; idx < DIM; ++idx) {
            float rr = Ur[idx][j] * Ur[idx][k] + Ui[idx][j] * Ui[idx][k];
            a0 += (idx & 8) ? -rr : rr;
            a1 += (idx & 4) ? -rr : rr;
            a2 += (idx & 2) ? -rr : rr;
            a3 += (idx & 1) ? -rr : rr;
        }
        A[0][j][k] = a0; A[1][j][k] = a1; A[2][j][k] = a2; A[3][j][k] = a3;
    }
    __syncthreads();

    // K transform: 324 scalars to global (grid-stride: 324 > 256)
    for (int id = threadIdx.x; id < 4 * 81; id += blockDim.x) {
        int w = id & 3, u = id >> 2;
        int e0 = u / 27, e1 = (u / 9) % 3, e2 = (u / 3) % 3, e3 = u % 3;
        int m  = ((e0 == 2) ? 8 : 0) | ((e1 == 2) ? 4 : 0) | ((e2 == 2) ? 2 : 0) | ((e3 == 2) ? 1 : 0);
        int d1 = ((e0 == 1) ? 8 : 0) | ((e1 == 1) ? 4 : 0) | ((e2 == 1) ? 2 : 0) | ((e3 == 1) ? 1 : 0);
        float acc = 0.f;
#pragma unroll
        for (int b = 0; b < DIM; ++b) {
            float sgn = (__popc(b & d1) & 1) ? -1.f : 1.f;
            acc += sgn * A[w][b][b ^ m];
        }
        gk[u * 4 + w] = 0.0625f * acc;
    }
}

// ---------------- Kernel B: pure streaming contraction ----------------
// Stages the 81 float4 coefficients into LDS once per block, then a fully
// static-unrolled 9x9xSPT contraction. No phase-1 code in this kernel's
// register allocation.
__global__ __launch_bounds__(256) void contract_kernel(const float4* __restrict__ x,
                                                       const float4* __restrict__ gk,
                                                       float4* __restrict__ out, int quarter) {
    __shared__ float4 lk[81];

    int tid = blockIdx.x * blockDim.x + threadIdx.x;
    bool valid = tid < quarter;

    // Issue sample loads first — latency hides behind the LDS staging barrier.
    float4 xs[SPT];
    sfor<SPT>([&](auto S) {
        xs[S.v] = valid ? x[tid + S.v * quarter] : make_float4(0.f, 0.f, 0.f, 0.f);
    });

    if (threadIdx.x < 81) lk[threadIdx.x] = gk[threadIdx.x];
    __syncthreads();

    float t9[SPT][9], u9[SPT][9];
    sfor<SPT>([&](auto S) {
        build9(xs[S.v].x, xs[S.v].y, t9[S.v]);
        build9(xs[S.v].z, xs[S.v].w, u9[S.v]);
    });

    float4 acc[SPT];
    sfor<SPT>([&](auto S) { acc[S.v] = make_float4(0.f, 0.f, 0.f, 0.f); });

    sfor<9>([&](auto I) {
        sfor<9>([&](auto J) {
            float4 c = lk[I.v * 9 + J.v];   // ds_read_b128, imm offset, broadcast
            sfor<SPT>([&](auto S) {
                float p = t9[S.v][I.v] * u9[S.v][J.v];
                acc[S.v].x = fmaf(c.x, p, acc[S.v].x);
                acc[S.v].y = fmaf(c.y, p, acc[S.v].y);
                acc[S.v].z = fmaf(c.z, p, acc[S.v].z);
                acc[S.v].w = fmaf(c.w, p, acc[S.v].w);
            });
        });
    });

    if (!valid) return;
    sfor<SPT>([&](auto S) { out[tid + S.v * quarter] = acc[S.v]; });
}

extern "C" void kernel_launch(void* const* d_in, const int* in_sizes, int n_in,
                              void* d_out, int out_size, void* d_ws, size_t ws_size,
                              hipStream_t stream) {
    const float* x = (const float*)d_in[0];
    const float* wt = (const float*)d_in[1];
    float* out = (float*)d_out;
    float* gk = (float*)d_ws;        // 324 floats = 1296 B of workspace
    (void)ws_size; (void)n_in; (void)out_size;

    int B = in_sizes[0] / NQ;        // 2^20 samples
    int quarter = B / SPT;           // 4 samples per thread
    int blocks = (quarter + 255) / 256;   // 1024 blocks = 4/CU

    setup_kernel<<<1, 256, 0, stream>>>(wt, gk);
    contract_kernel<<<blocks, 256, 0, stream>>>((const float4*)x, (const float4*)gk,
                                                (float4*)out, quarter);
}

// Round 3
// 82.916 us; speedup vs baseline: 1.0280x; 1.0280x over previous
//
#include <hip/hip_runtime.h>

#define NQ 4
#define DIM 16

struct cplx { float r, i; };
__device__ inline cplx cmul(cplx a, cplx b) { return {a.r*b.r - a.i*b.i, a.r*b.i + a.i*b.r}; }
__device__ inline cplx cadd(cplx a, cplx b) { return {a.r + b.r, a.i + b.i}; }

// compile-time for-loop: every array index below is a constant by construction
// (rule #20 defense: runtime-indexed arrays go to scratch).
template<int I> struct ic { static constexpr int v = I; };
template<int N, typename F> __device__ __forceinline__ void sfor(F f) {
    if constexpr (N > 0) { sfor<N - 1>(f); f(ic<N - 1>{}); }
}

// t[9] = (1, cv, sv, cu, cu*cv, cu*sv, su, su*cv, su*sv)
__device__ __forceinline__ void build9(float u, float v, float* t) {
    float su, cu, sv, cv;
    __sincosf(u, &su, &cu);
    __sincosf(v, &sv, &cv);
    t[0] = 1.f;      t[1] = cv;      t[2] = sv;
    t[3] = cu;       t[4] = cu * cv; t[5] = cu * sv;
    t[6] = su;       t[7] = su * cv; t[8] = su * sv;
}

// The 324 coefficients live in constant address space: the contraction reads them
// via s_load on the SCALAR pipe (K$-resident, wave-uniform broadcast for free).
// This removes all LDS traffic, the staging barrier, and the per-CU LDS-pipe
// bottleneck (81 ds_read_b128/wave at ~12 cyc was the issue-rate floor).
__constant__ float4 cK[81];

// ---------------- Kernel A: build the 324 trig-basis coefficients ----------------
//   out_w = sum_{e in {1,cos,sin}^4} K_w[e] * prod_q f_{e_q}(x_q)
//   K_w[e] = (1/16) sum_b A_w[b][b^m] * parity(b & d1)   (m=sin-bits, d1=cos-bits)
//   A_w[j][k] = sum_idx sign_w(idx) * (Ur[idx][j]Ur[idx][k] + Ui[idx][j]Ui[idx][k])
// Writes straight into cK's backing store (address passed from host).
// Cross-kernel visibility = standard dispatch-boundary release/acquire (same
// dependency the d_ws version relied on; K$/L1 invalidate at dispatch).
__global__ __launch_bounds__(256) void setup_kernel(const float* __restrict__ wt,
                                                    float* __restrict__ gk) {
    __shared__ float Ur[DIM][DIM];
    __shared__ float Ui[DIM][DIM];
    __shared__ float A[4][DIM][DIM];

    int col = threadIdx.x;
    if (col < DIM) {
        float ar[DIM], ai[DIM];
#pragma unroll
        for (int i = 0; i < DIM; ++i) { ar[i] = 0.f; ai[i] = 0.f; }
        ar[col] = 1.f;
#pragma unroll
        for (int l = 0; l < 2; ++l) {
#pragma unroll
            for (int q = 0; q < NQ; ++q) {
                float tx = wt[(l * 4 + q) * 3 + 0];
                float ty = wt[(l * 4 + q) * 3 + 1];
                float tz = wt[(l * 4 + q) * 3 + 2];
                float cx, sx, cy, sy, cz, sz;
                __sincosf(0.5f * tx, &sx, &cx);
                __sincosf(0.5f * ty, &sy, &cy);
                __sincosf(0.5f * tz, &sz, &cz);
                cplx Rx[2][2] = {{{cx, 0.f}, {0.f, -sx}}, {{0.f, -sx}, {cx, 0.f}}};
                cplx Ry[2][2] = {{{cy, 0.f}, {-sy, 0.f}}, {{sy, 0.f}, {cy, 0.f}}};
                cplx Rz[2][2] = {{{cz, -sz}, {0.f, 0.f}}, {{0.f, 0.f}, {cz, sz}}};
                cplx T[2][2], G[2][2];
#pragma unroll
                for (int r = 0; r < 2; ++r)
#pragma unroll
                    for (int c = 0; c < 2; ++c)
                        T[r][c] = cadd(cmul(Ry[r][0], Rx[0][c]), cmul(Ry[r][1], Rx[1][c]));
#pragma unroll
                for (int r = 0; r < 2; ++r)
#pragma unroll
                    for (int c = 0; c < 2; ++c)
                        G[r][c] = cadd(cmul(Rz[r][0], T[0][c]), cmul(Rz[r][1], T[1][c]));
                int pos = 3 - q, mask = 1 << pos;
#pragma unroll
                for (int idx = 0; idx < DIM; ++idx) {
                    if (idx & mask) continue;
                    int i1 = idx | mask;
                    cplx a0 = {ar[idx], ai[idx]}, a1 = {ar[i1], ai[i1]};
                    cplx n0 = cadd(cmul(G[0][0], a0), cmul(G[0][1], a1));
                    cplx n1 = cadd(cmul(G[1][0], a0), cmul(G[1][1], a1));
                    ar[idx] = n0.r; ai[idx] = n0.i;
                    ar[i1] = n1.r;  ai[i1] = n1.i;
                }
            }
#pragma unroll
            for (int q = 0; q < NQ; ++q) {
                int cpos = 3 - q, tpos = 3 - ((q + 1) & 3);
                int tmask = 1 << tpos;
#pragma unroll
                for (int idx = 0; idx < DIM; ++idx) {
                    if (((idx >> cpos) & 1) && !((idx >> tpos) & 1)) {
                        int i1 = idx | tmask;
                        float tr = ar[idx]; ar[idx] = ar[i1]; ar[i1] = tr;
                        float ti = ai[idx]; ai[idx] = ai[i1]; ai[i1] = ti;
                    }
                }
            }
        }
#pragma unroll
        for (int i = 0; i < DIM; ++i) { Ur[i][col] = ar[i]; Ui[i][col] = ai[i]; }
    }
    __syncthreads();

    // A_w[j][k], one (j,k) per thread; 4 outputs share the products
    {
        int j = threadIdx.x >> 4, k = threadIdx.x & 15;
        float a0 = 0.f, a1 = 0.f, a2 = 0.f, a3 = 0.f;
#pragma unroll
        for (int idx = 0; idx < DIM; ++idx) {
            float rr = Ur[idx][j] * Ur[idx][k] + Ui[idx][j] * Ui[idx][k];
            a0 += (idx & 8) ? -rr : rr;
            a1 += (idx & 4) ? -rr : rr;
            a2 += (idx & 2) ? -rr : rr;
            a3 += (idx & 1) ? -rr : rr;
        }
        A[0][j][k] = a0; A[1][j][k] = a1; A[2][j][k] = a2; A[3][j][k] = a3;
    }
    __syncthreads();

    // K transform: 324 scalars to the constant-memory backing store
    for (int id = threadIdx.x; id < 4 * 81; id += blockDim.x) {
        int w = id & 3, u = id >> 2;
        int e0 = u / 27, e1 = (u / 9) % 3, e2 = (u / 3) % 3, e3 = u % 3;
        int m  = ((e0 == 2) ? 8 : 0) | ((e1 == 2) ? 4 : 0) | ((e2 == 2) ? 2 : 0) | ((e3 == 2) ? 1 : 0);
        int d1 = ((e0 == 1) ? 8 : 0) | ((e1 == 1) ? 4 : 0) | ((e2 == 1) ? 2 : 0) | ((e3 == 1) ? 1 : 0);
        float acc = 0.f;
#pragma unroll
        for (int b = 0; b < DIM; ++b) {
            float sgn = (__popc(b & d1) & 1) ? -1.f : 1.f;
            acc += sgn * A[w][b][b ^ m];
        }
        gk[u * 4 + w] = 0.0625f * acc;
    }
}

// ---------------- Kernel B: pure-VALU streaming contraction ----------------
// No LDS, no barrier, no vector loads of K. SPT=2 keeps the live set (~60
// floats) comfortably in registers — the round-1 56-VGPR spill trap came from
// SPT=4's ~100-float working set. Arithmetic order identical to the passing
// kernel (absmax margin preserved).
__global__ __launch_bounds__(256) void contract_kernel(const float4* __restrict__ x,
                                                       float4* __restrict__ out, int half) {
    int tid = blockIdx.x * blockDim.x + threadIdx.x;
    if (tid >= half) return;
    float4 xa = x[tid];
    float4 xb = x[tid + half];

    float ta[9], ua[9], tb[9], ub[9];
    build9(xa.x, xa.y, ta);  build9(xa.z, xa.w, ua);
    build9(xb.x, xb.y, tb);  build9(xb.z, xb.w, ub);

    float4 accA = make_float4(0.f, 0.f, 0.f, 0.f);
    float4 accB = make_float4(0.f, 0.f, 0.f, 0.f);

    sfor<9>([&](auto I) {
        sfor<9>([&](auto J) {
            const float4 c = cK[I.v * 9 + J.v];   // s_load_dwordx4, scalar pipe, K$-hit
            float pa = ta[I.v] * ua[J.v];
            float pb = tb[I.v] * ub[J.v];
            accA.x = fmaf(c.x, pa, accA.x);
            accA.y = fmaf(c.y, pa, accA.y);
            accA.z = fmaf(c.z, pa, accA.z);
            accA.w = fmaf(c.w, pa, accA.w);
            accB.x = fmaf(c.x, pb, accB.x);
            accB.y = fmaf(c.y, pb, accB.y);
            accB.z = fmaf(c.z, pb, accB.z);
            accB.w = fmaf(c.w, pb, accB.w);
        });
    });

    out[tid] = accA;
    out[tid + half] = accB;
}

extern "C" void kernel_launch(void* const* d_in, const int* in_sizes, int n_in,
                              void* d_out, int out_size, void* d_ws, size_t ws_size,
                              hipStream_t stream) {
    const float* x = (const float*)d_in[0];
    const float* wt = (const float*)d_in[1];
    float* out = (float*)d_out;
    (void)d_ws; (void)ws_size; (void)n_in; (void)out_size;

    // Resolve the constant-memory backing store once (runtime query, no stream op —
    // graph-capture safe). The setup kernel writes it; dispatch-boundary
    // release/acquire makes it visible to contract_kernel's s_loads.
    static float* gk_const = nullptr;
    if (!gk_const) hipGetSymbolAddress((void**)&gk_const, HIP_SYMBOL(cK));

    int B = in_sizes[0] / NQ;     // 2^20 samples
    int half = B / 2;             // 2 samples per thread
    int blocks = (half + 255) / 256;   // 2048 blocks = 8/CU

    setup_kernel<<<1, 256, 0, stream>>>(wt, gk_const);
    contract_kernel<<<blocks, 256, 0, stream>>>((const float4*)x, (float4*)out, half);
}